// Round 1
// baseline (916.083 us; speedup 1.0000x reference)
//
#include <hip/hip_runtime.h>
#include <hip/hip_bf16.h>

#define DIM 300

using shortx4 = __attribute__((ext_vector_type(4))) short;
using shortx8 = __attribute__((ext_vector_type(8))) short;
using floatx4 = __attribute__((ext_vector_type(4))) float;

__device__ __forceinline__ short f2bf(float f) {
  union { __hip_bfloat16 h; short s; } u;
  u.h = __float2bfloat16(f);
  return u.s;
}

// Pack Ws (fp32 [5][300][300], row n = out-feature, col k = in-feature) into
// bf16 MFMA B-fragments in d_ws. B[k][n] = W[n][k]. Padded: n->304 (19 tiles
// of 16), k->320 (10 iters of 32), zeros in the pad.
// frag(s,nt,kk) is 1KB: lane l holds the 8 contiguous bf16
// W[n = nt*16 + (l&15)][k = kk*32 + (l>>4)*8 + j], j=0..7.
__global__ void prep_w_kernel(const float* __restrict__ Ws, short* __restrict__ wsB) {
  int t = blockIdx.x * 256 + threadIdx.x;
  if (t >= 5 * 19 * 10 * 64) return;
  int fid = t >> 6, lane = t & 63;
  int s = fid / 190; int rem = fid - s * 190;
  int nt = rem / 10; int kk = rem - nt * 10;
  int n  = nt * 16 + (lane & 15);
  int k0 = kk * 32 + (lane >> 4) * 8;
  shortx8 v;
  #pragma unroll
  for (int j = 0; j < 8; ++j) {
    int k = k0 + j;
    float f = (n < DIM && k < DIM) ? Ws[s * (DIM * DIM) + n * DIM + k] : 0.0f;
    v[j] = f2bf(f);
  }
  *reinterpret_cast<shortx8*>(wsB + (size_t)fid * 512 + lane * 8) = v;
}

// ======================= FAST PATH (needs ~122 MB ws) =======================
// Stage 1: streaming group-sum kernel. One block = 64 groups of scale R.
// Writes bf16 sums row-major [row][320] (k padded 300->320 with zeros) into
// Arow at global row 64*bid + m (grid order == main-kernel grid order, so the
// base row is just 64*bid). All loads and the 1KB/wave stores are fully
// coalesced; no LDS, no barriers.
template <int R>
__device__ __forceinline__ void sum_tile(
    const float* __restrict__ x, short* __restrict__ Arow,
    int tile, int bid, int N)
{
  const int tid = threadIdx.x;
  const int groups = N / R;                  // N divisible by all scales
  const int g0 = tile * 64;
  int validM = groups - g0; if (validM > 64) validM = 64;
  short* dst = Arow + (size_t)bid * (64 * 320);

  // 64 rows x 40 k-octets (8 bf16 = one 16B store each). 2560 = 10*256 exact.
  for (int idx = tid; idx < 64 * 40; idx += 256) {
    int m  = idx / 40;
    int ko = idx - m * 40;                   // octet: k = ko*8 .. ko*8+7
    float a0=0.f,a1=0.f,a2=0.f,a3=0.f,a4=0.f,a5=0.f,a6=0.f,a7=0.f;
    if (m < validM) {
      const float* p = x + ((size_t)(g0 + m) * R) * DIM + ko * 8;
      const bool lo = (ko * 2     < 75);     // float4 slot ko*2   valid (k<300)
      const bool hi = (ko * 2 + 1 < 75);     // float4 slot ko*2+1 valid
      #pragma unroll
      for (int j = 0; j < R; ++j) {
        if (lo) {
          float4 v = *reinterpret_cast<const float4*>(p + j * DIM);
          a0 += v.x; a1 += v.y; a2 += v.z; a3 += v.w;
        }
        if (hi) {
          float4 v = *reinterpret_cast<const float4*>(p + j * DIM + 4);
          a4 += v.x; a5 += v.y; a6 += v.z; a7 += v.w;
        }
      }
    }
    shortx8 v;
    v[0]=f2bf(a0); v[1]=f2bf(a1); v[2]=f2bf(a2); v[3]=f2bf(a3);
    v[4]=f2bf(a4); v[5]=f2bf(a5); v[6]=f2bf(a6); v[7]=f2bf(a7);
    *reinterpret_cast<shortx8*>(dst + m * 320 + ko * 8) = v;
  }
}

__global__ __launch_bounds__(256) void sum_kernel(
    const float* __restrict__ x, short* __restrict__ Arow,
    int N, int b0, int b1, int b2, int b3)
{
  const int bid = blockIdx.x;
  if (bid < b0)      sum_tile<25>(x, Arow, bid,      bid, N);
  else if (bid < b1) sum_tile<10>(x, Arow, bid - b0, bid, N);
  else if (bid < b2) sum_tile<4> (x, Arow, bid - b1, bid, N);
  else if (bid < b3) sum_tile<2> (x, Arow, bid - b2, bid, N);
  else               sum_tile<1> (x, Arow, bid - b3, bid, N);
}

// Stage 2: GEMM + expansion. A-fragments preload straight from global (L3-hot,
// written by sum_kernel) into registers -> no LDS staging phase, ONE barrier.
// LDS = Stage[64][312] bf16 (39936 B) only -> 4 blocks/CU.
template <int R>
__device__ __forceinline__ void run_tile2(
    const float* __restrict__ bs, float* __restrict__ out,
    const short* __restrict__ wsB, const short* __restrict__ Arow,
    int si, int tile, int bid, int N, short* Stage)
{
  const int tid = threadIdx.x;
  const int groups = N / R;
  const int g0 = tile * 64;
  int validM = groups - g0; if (validM > 64) validM = 64;

  const int lane = tid & 63;
  const int wave = tid >> 6;
  const int lr   = lane & 15;
  const int quad = lane >> 4;
  const int wm   = wave * 16;

  // A fragment: lane l holds sums[row = 64*bid + wm + lr][k = kk*32 + quad*8 + j].
  // 16B loads; 16 rows x 64B contiguous chunks per kk (L2/L3-served).
  const short* arow = Arow + ((size_t)bid * 64 + wm + lr) * 320 + quad * 8;
  shortx8 af[10];
  #pragma unroll
  for (int kk = 0; kk < 10; ++kk)
    af[kk] = *reinterpret_cast<const shortx8*>(arow + kk * 32);

  const float inv_r = 1.0f / (float)R;
  const short* wb = wsB + (size_t)si * 190 * 512 + lane * 8;

  #pragma unroll 1
  for (int nt = 0; nt < 19; ++nt) {
    floatx4 acc = {0.f, 0.f, 0.f, 0.f};
    const short* wnt = wb + nt * 10 * 512;
    #pragma unroll
    for (int kk = 0; kk < 10; ++kk) {
      shortx8 bf = *reinterpret_cast<const shortx8*>(wnt + kk * 512);
      acc = __builtin_amdgcn_mfma_f32_16x16x32_bf16(af[kk], bf, acc, 0, 0, 0);
    }
    // C/D layout: col = lane&15, row = quad*4 + reg  [m89/m91]
    const int n = nt * 16 + lr;               // <= 303
    const float b = (n < DIM) ? bs[si * DIM + n] : 0.0f;  // L1-hot broadcast
    #pragma unroll
    for (int j = 0; j < 4; ++j) {
      float v = acc[j] + b;
      v = v > 0.f ? v * inv_r : 0.f;
      Stage[(wm + quad * 4 + j) * 312 + n] = f2bf(v);
    }
  }
  __syncthreads();

  // Expansion: dense float4 stores over the block's contiguous out range.
  float4* __restrict__ outv =
      reinterpret_cast<float4*>(out) + ((size_t)si * N + (size_t)g0 * R) * 75;
  const int total = validM * R * 75;
  for (int f = tid; f < total; f += 256) {
    int mr = f / 75;                  // out-row within block
    int c  = f - mr * 75;             // float4 col
    int sm = mr / R;                  // source h row (const div)
    int2 d = *reinterpret_cast<const int2*>(&Stage[sm * 312 + c * 4]);
    float4 o;
    o.x = __uint_as_float(((unsigned)d.x) << 16);
    o.y = __uint_as_float(((unsigned)d.x) & 0xffff0000u);
    o.z = __uint_as_float(((unsigned)d.y) << 16);
    o.w = __uint_as_float(((unsigned)d.y) & 0xffff0000u);
    outv[f] = o;
  }
}

__global__ __launch_bounds__(256, 4) void ce_main2_kernel(
    const float* __restrict__ bs, float* __restrict__ out,
    const short* __restrict__ wsB, const short* __restrict__ Arow,
    int N, int b0, int b1, int b2, int b3)
{
  __shared__ __align__(16) short Stage[64 * 312];   // 39936 B -> 4 blocks/CU
  const int bid = blockIdx.x;
  if (bid < b0)      run_tile2<25>(bs, out, wsB, Arow, 4, bid,      bid, N, Stage);
  else if (bid < b1) run_tile2<10>(bs, out, wsB, Arow, 3, bid - b0, bid, N, Stage);
  else if (bid < b2) run_tile2<4> (bs, out, wsB, Arow, 2, bid - b1, bid, N, Stage);
  else if (bid < b3) run_tile2<2> (bs, out, wsB, Arow, 1, bid - b2, bid, N, Stage);
  else               run_tile2<1> (bs, out, wsB, Arow, 0, bid - b3, bid, N, Stage);
}

// ================== FALLBACK PATH (ws too small): previous kernel ==================
template <int R>
__device__ __forceinline__ void run_tile(
    const float* __restrict__ x, const float* __restrict__ bs,
    float* __restrict__ out, const short* __restrict__ wsB,
    int si, int tile, int N, short* A, float* bsh)
{
  const int tid = threadIdx.x;
  const int groups = N / R;
  const int g0 = tile * 64;
  int validM = groups - g0; if (validM > 64) validM = 64;

  for (int t = tid; t < 304; t += 256) bsh[t] = (t < DIM) ? bs[si * DIM + t] : 0.0f;

  for (int idx = tid; idx < 64 * 82; idx += 256) {
    int m  = idx / 82;
    int kv = idx - m * 82;
    float ax = 0.f, ay = 0.f, az = 0.f, aw = 0.f;
    if (kv < 75 && m < validM) {
      const float* p = x + ((size_t)(g0 + m) * R) * DIM + kv * 4;
      #pragma unroll
      for (int j = 0; j < R; ++j) {
        float4 v = *reinterpret_cast<const float4*>(p + j * DIM);
        ax += v.x; ay += v.y; az += v.z; aw += v.w;
      }
    }
    shortx4 h;
    h[0] = f2bf(ax); h[1] = f2bf(ay); h[2] = f2bf(az); h[3] = f2bf(aw);
    *reinterpret_cast<shortx4*>(&A[m * 328 + kv * 4]) = h;
  }
  __syncthreads();

  const int lane = tid & 63;
  const int wave = tid >> 6;
  const int lr   = lane & 15;
  const int quad = lane >> 4;
  const int wm   = wave * 16;

  shortx8 af[10];
  #pragma unroll
  for (int kk = 0; kk < 10; ++kk)
    af[kk] = *reinterpret_cast<const shortx8*>(&A[(wm + lr) * 328 + kk * 32 + quad * 8]);
  __syncthreads();

  short* Stage = A;
  const float inv_r = 1.0f / (float)R;
  const short* wb = wsB + (size_t)si * 190 * 512 + lane * 8;

  #pragma unroll 1
  for (int nt = 0; nt < 19; ++nt) {
    floatx4 acc = {0.f, 0.f, 0.f, 0.f};
    const short* wnt = wb + nt * 10 * 512;
    #pragma unroll
    for (int kk = 0; kk < 10; ++kk) {
      shortx8 bf = *reinterpret_cast<const shortx8*>(wnt + kk * 512);
      acc = __builtin_amdgcn_mfma_f32_16x16x32_bf16(af[kk], bf, acc, 0, 0, 0);
    }
    const int n = nt * 16 + lr;
    const float b = bsh[n];
    #pragma unroll
    for (int j = 0; j < 4; ++j) {
      float v = acc[j] + b;
      v = v > 0.f ? v * inv_r : 0.f;
      Stage[(wm + quad * 4 + j) * 312 + n] = f2bf(v);
    }
  }
  __syncthreads();

  float4* __restrict__ outv =
      reinterpret_cast<float4*>(out) + ((size_t)si * N + (size_t)g0 * R) * 75;
  const int total = validM * R * 75;
  for (int f = tid; f < total; f += 256) {
    int mr = f / 75;
    int c  = f - mr * 75;
    int sm = mr / R;
    int2 d = *reinterpret_cast<const int2*>(&Stage[sm * 312 + c * 4]);
    float4 o;
    o.x = __uint_as_float(((unsigned)d.x) << 16);
    o.y = __uint_as_float(((unsigned)d.x) & 0xffff0000u);
    o.z = __uint_as_float(((unsigned)d.y) << 16);
    o.w = __uint_as_float(((unsigned)d.y) & 0xffff0000u);
    outv[f] = o;
  }
}

__global__ __launch_bounds__(256) void ce_main_kernel(
    const float* __restrict__ x, const float* __restrict__ bs,
    float* __restrict__ out, const short* __restrict__ wsB,
    int N, int b0, int b1, int b2, int b3)
{
  __shared__ __align__(16) short A[64 * 328];
  __shared__ float bsh[304];
  const int bid = blockIdx.x;
  if (bid < b0)      run_tile<25>(x, bs, out, wsB, 4, bid,      N, A, bsh);
  else if (bid < b1) run_tile<10>(x, bs, out, wsB, 3, bid - b0, N, A, bsh);
  else if (bid < b2) run_tile<4> (x, bs, out, wsB, 2, bid - b1, N, A, bsh);
  else if (bid < b3) run_tile<2> (x, bs, out, wsB, 1, bid - b2, N, A, bsh);
  else               run_tile<1> (x, bs, out, wsB, 0, bid - b3, N, A, bsh);
}

extern "C" void kernel_launch(void* const* d_in, const int* in_sizes, int n_in,
                              void* d_out, int out_size, void* d_ws, size_t ws_size,
                              hipStream_t stream) {
  const float* x  = (const float*)d_in[0];
  const float* Ws = (const float*)d_in[1];
  const float* bs = (const float*)d_in[2];
  float* out = (float*)d_out;
  short* wsB = (short*)d_ws;                 // 972,800 B for W fragments

  const int N = in_sizes[0] / DIM;           // 100000

  prep_w_kernel<<<(5 * 19 * 10 * 64 + 255) / 256, 256, 0, stream>>>(Ws, wsB);

  const int t25 = (N / 25 + 63) / 64;
  const int t10 = (N / 10 + 63) / 64;
  const int t4  = (N / 4  + 63) / 64;
  const int t2  = (N / 2  + 63) / 64;
  const int t1  = (N      + 63) / 64;
  const int b0 = t25;
  const int b1 = b0 + t10;
  const int b2 = b1 + t4;
  const int b3 = b2 + t2;
  const int total = b3 + t1;

  const size_t wsB_bytes = 972800;           // 5*190 frags * 1KB
  const size_t arow_bytes = (size_t)total * 64 * 320 * sizeof(short);

  if (ws_size >= wsB_bytes + arow_bytes) {
    short* Arow = wsB + wsB_bytes / sizeof(short);   // 16B-aligned offset
    sum_kernel<<<total, 256, 0, stream>>>(x, Arow, N, b0, b1, b2, b3);
    ce_main2_kernel<<<total, 256, 0, stream>>>(bs, out, wsB, Arow, N, b0, b1, b2, b3);
  } else {
    // Workspace too small for the split path: previous single-kernel version.
    ce_main_kernel<<<total, 256, 0, stream>>>(x, bs, out, wsB, N, b0, b1, b2, b3);
  }
}

// Round 2
// 837.852 us; speedup vs baseline: 1.0934x; 1.0934x over previous
//
#include <hip/hip_runtime.h>
#include <hip/hip_bf16.h>

#define DIM 300

using shortx8 = __attribute__((ext_vector_type(8))) short;
using floatx4 = __attribute__((ext_vector_type(4))) float;

__device__ __forceinline__ short f2bf(float f) {
  union { __hip_bfloat16 h; short s; } u;
  u.h = __float2bfloat16(f);
  return u.s;
}

// Pack Ws (fp32 [5][300][300], row n = out-feature, col k = in-feature) into
// bf16 MFMA B-fragments in d_ws. B[k][n] = W[n][k]. Padded: n->304 (19 tiles
// of 16), k->320 (10 iters of 32), zeros in the pad.
// frag(s,nt,kk) is 1KB: lane l holds the 8 contiguous bf16
// W[n = nt*16 + (l&15)][k = kk*32 + (l>>4)*8 + j], j=0..7.
__global__ void prep_w_kernel(const float* __restrict__ Ws, short* __restrict__ wsB) {
  int t = blockIdx.x * 256 + threadIdx.x;
  if (t >= 5 * 19 * 10 * 64) return;
  int fid = t >> 6, lane = t & 63;
  int s = fid / 190; int rem = fid - s * 190;
  int nt = rem / 10; int kk = rem - nt * 10;
  int n  = nt * 16 + (lane & 15);
  int k0 = kk * 32 + (lane >> 4) * 8;
  shortx8 v;
  #pragma unroll
  for (int j = 0; j < 8; ++j) {
    int k = k0 + j;
    float f = (n < DIM && k < DIM) ? Ws[s * (DIM * DIM) + n * DIM + k] : 0.0f;
    v[j] = f2bf(f);
  }
  *reinterpret_cast<shortx8*>(wsB + (size_t)fid * 512 + lane * 8) = v;
}

// One block = 64 consecutive groups of scale R; each of the 4 waves owns 16
// groups end-to-end (stage sums -> fragments -> MFMA -> h -> expansion), all
// through a wave-private 16-row slice of LDS A[64][320] bf16 (40960 B exactly
// -> 4 blocks/CU). ZERO __syncthreads: every LDS RAW is intra-wave (in-order
// LDS pipe + compiler lgkmcnt).
//
// Stage-A layout is k-octet XOR-swizzled: data octet ko of row m lives at
// octet (ko ^ (m&7)). Row stride 640 B is bank-aligned (=0 mod 128 B), so a
// linear layout would make the 16-rows-same-column fragment preload a 16-way
// bank conflict; the swizzle spreads the 8 low octets -> 2-way (free, m136).
// After the preload the sums are dead and the h/expansion reuse is linear.
template <int R>
__device__ __forceinline__ void run_tile(
    const float* __restrict__ x, const float* __restrict__ bs,
    float* __restrict__ out, const short* __restrict__ wsB,
    int si, int tile, int N, short* A)
{
  const int tid  = threadIdx.x;
  const int lane = tid & 63;
  const int wave = tid >> 6;
  const int wm   = wave * 16;
  const int groups = N / R;                  // N divisible by all scales
  const int g0 = tile * 64;
  int validM = groups - g0; if (validM > 64) validM = 64;

  // ---- Stage-A (wave-private): 16 rows x 40 k-octets = 640 = 10 iters/lane.
  // Octet ko covers k = 8ko..8ko+7; float4 lo valid k<300 iff ko<=37, hi iff
  // ko<=36 (ko 37 is the 296..299 half; 38,39 pure pad -> zeros).
  for (int idx = lane; idx < 640; idx += 64) {
    int ml = idx / 40;
    int ko = idx - ml * 40;
    int m  = wm + ml;
    float a0=0.f,a1=0.f,a2=0.f,a3=0.f,a4=0.f,a5=0.f,a6=0.f,a7=0.f;
    if (m < validM) {
      const float* p = x + ((size_t)(g0 + m) * R) * DIM + ko * 8;
      const bool lo = (ko <= 37);
      const bool hi = (ko <= 36);
      #pragma unroll
      for (int j = 0; j < R; ++j) {
        if (lo) {
          float4 v = *reinterpret_cast<const float4*>(p + j * DIM);
          a0 += v.x; a1 += v.y; a2 += v.z; a3 += v.w;
        }
        if (hi) {
          float4 v = *reinterpret_cast<const float4*>(p + j * DIM + 4);
          a4 += v.x; a5 += v.y; a6 += v.z; a7 += v.w;
        }
      }
    }
    shortx8 v8;
    v8[0]=f2bf(a0); v8[1]=f2bf(a1); v8[2]=f2bf(a2); v8[3]=f2bf(a3);
    v8[4]=f2bf(a4); v8[5]=f2bf(a5); v8[6]=f2bf(a6); v8[7]=f2bf(a7);
    *reinterpret_cast<shortx8*>(&A[m * 320 + ((ko ^ (ml & 7)) * 8)]) = v8;
  }

  // ---- Fragment preload (wave-private rows; no barrier needed).
  // af[kk]: lane l holds sums[row = wm + (l&15)][k = kk*32 + (l>>4)*8 + j].
  // Data octet index = kk*4 + quad, stored at (kk*4+quad) ^ (lr&7).
  const int lr   = lane & 15;
  const int quad = lane >> 4;
  shortx8 af[10];
  #pragma unroll
  for (int kk = 0; kk < 10; ++kk) {
    int oct = (kk * 4 + quad) ^ (lr & 7);
    af[kk] = *reinterpret_cast<const shortx8*>(&A[(wm + lr) * 320 + oct * 8]);
  }

  // ---- GEMM: 19 n-tiles x 10 k-steps; h written back into own rows (linear).
  const float inv_r = 1.0f / (float)R;
  const short* wb = wsB + (size_t)si * 190 * 512 + lane * 8;

  #pragma unroll 1
  for (int nt = 0; nt < 19; ++nt) {
    floatx4 acc = {0.f, 0.f, 0.f, 0.f};
    const short* wnt = wb + nt * 10 * 512;
    #pragma unroll
    for (int kk = 0; kk < 10; ++kk) {
      shortx8 bf = *reinterpret_cast<const shortx8*>(wnt + kk * 512);
      acc = __builtin_amdgcn_mfma_f32_16x16x32_bf16(af[kk], bf, acc, 0, 0, 0);
    }
    // C/D layout: col = lane&15, row = quad*4 + reg  [m89/m91]
    const int n = nt * 16 + lr;                         // <= 303
    const float b = (n < DIM) ? bs[si * DIM + n] : 0.0f; // L1-hot broadcast
    #pragma unroll
    for (int j = 0; j < 4; ++j) {
      float v = acc[j] + b;
      v = v > 0.f ? v * inv_r : 0.f;
      A[(wm + quad * 4 + j) * 320 + n] = f2bf(v);
    }
  }

  // ---- Expansion (wave-private): out rows [(g0+wm)*R, (g0+wm+vmw)*R) of
  // scale si; dense float4 stores, 75 per row, fully coalesced per wave.
  int vmw = validM - wm; if (vmw > 16) vmw = 16; if (vmw < 0) vmw = 0;
  float4* __restrict__ outv =
      reinterpret_cast<float4*>(out) + ((size_t)si * N + (size_t)(g0 + wm) * R) * 75;
  const short* src = A + wm * 320;
  const int total = vmw * R * 75;
  for (int f = lane; f < total; f += 64) {
    int mr = f / 75;                  // local out-row (0..16R)
    int c  = f - mr * 75;             // float4 col
    int sm = mr / R;                  // local source h row (const div)
    int2 d = *reinterpret_cast<const int2*>(&src[sm * 320 + c * 4]);
    float4 o;
    o.x = __uint_as_float(((unsigned)d.x) << 16);
    o.y = __uint_as_float(((unsigned)d.x) & 0xffff0000u);
    o.z = __uint_as_float(((unsigned)d.y) << 16);
    o.w = __uint_as_float(((unsigned)d.y) & 0xffff0000u);
    outv[f] = o;
  }
}

__global__ __launch_bounds__(256, 4) void ce_main_kernel(
    const float* __restrict__ x, const float* __restrict__ bs,
    float* __restrict__ out, const short* __restrict__ wsB,
    int N, int b0, int b1, int b2, int b3)
{
  __shared__ __align__(16) short A[64 * 320];   // 40960 B -> exactly 4 blocks/CU
  const int bid = blockIdx.x;
  // Grid ordered descending r so the heavy r=25 blocks launch first.
  if (bid < b0)      run_tile<25>(x, bs, out, wsB, 4, bid,      N, A);
  else if (bid < b1) run_tile<10>(x, bs, out, wsB, 3, bid - b0, N, A);
  else if (bid < b2) run_tile<4> (x, bs, out, wsB, 2, bid - b1, N, A);
  else if (bid < b3) run_tile<2> (x, bs, out, wsB, 1, bid - b2, N, A);
  else               run_tile<1> (x, bs, out, wsB, 0, bid - b3, N, A);
}

extern "C" void kernel_launch(void* const* d_in, const int* in_sizes, int n_in,
                              void* d_out, int out_size, void* d_ws, size_t ws_size,
                              hipStream_t stream) {
  const float* x  = (const float*)d_in[0];
  const float* Ws = (const float*)d_in[1];
  const float* bs = (const float*)d_in[2];
  float* out = (float*)d_out;
  short* wsB = (short*)d_ws;                 // 972,800 B of scratch

  const int N = in_sizes[0] / DIM;           // 100000

  prep_w_kernel<<<(5 * 19 * 10 * 64 + 255) / 256, 256, 0, stream>>>(Ws, wsB);

  const int t25 = (N / 25 + 63) / 64;
  const int t10 = (N / 10 + 63) / 64;
  const int t4  = (N / 4  + 63) / 64;
  const int t2  = (N / 2  + 63) / 64;
  const int t1  = (N      + 63) / 64;
  const int b0 = t25;
  const int b1 = b0 + t10;
  const int b2 = b1 + t4;
  const int b3 = b2 + t2;
  const int total = b3 + t1;

  ce_main_kernel<<<total, 256, 0, stream>>>(x, bs, out, wsB, N, b0, b1, b2, b3);
}